// Round 10
// baseline (34.598 us; speedup 1.0000x reference)
//
#include <hip/hip_runtime.h>

typedef float f2 __attribute__((ext_vector_type(2)));   // complex (re, im)

constexpr int NQ   = 10;
constexpr int CDIM = 768;
constexpr int NL   = 3;
constexpr int NREG = 16;   // index bits 6..9 in the register index
constexpr int WPB  = 4;    // waves (= samples) per block

// ---------- cross-lane primitives (all VALU, no LDS pipe) ----------

template<int CTRL>
__device__ __forceinline__ float dppmov(float x) {
    return __int_as_float(__builtin_amdgcn_update_dpp(
        __float_as_int(x), __float_as_int(x), CTRL, 0xF, 0xF, true));
}

// y[l] = x[l ^ MASK] for MASK in {1,2,4,8}
template<int MASK>
__device__ __forceinline__ float lxor(float x, int lane) {
    static_assert(MASK == 1 || MASK == 2 || MASK == 4 || MASK == 8, "");
    if constexpr (MASK == 1)      return dppmov<0xB1>(x);   // quad_perm [1,0,3,2]
    else if constexpr (MASK == 2) return dppmov<0x4E>(x);   // quad_perm [2,3,0,1]
    else if constexpr (MASK == 4) {
        const float a = dppmov<0x104>(x);   // row_shl:4 -> src[i+4] (bit2=0 lanes)
        const float b = dppmov<0x114>(x);   // row_shr:4 -> src[i-4] (bit2=1 lanes)
        return ((lane >> 2) & 1) ? b : a;
    }
    else                          return dppmov<0x128>(x);  // row_ror:8 == xor8
}

// B in {4,5}: lo = x[l & ~(1<<B)], hi = x[l | (1<<B)]  (one swap instr)
template<int B>
__device__ __forceinline__ void swap2(float x, float& lo, float& hi) {
    const unsigned xu = __float_as_uint(x);
#if __has_builtin(__builtin_amdgcn_permlane16_swap) && __has_builtin(__builtin_amdgcn_permlane32_swap)
    if constexpr (B == 4) {
        auto r = __builtin_amdgcn_permlane16_swap(xu, xu, false, false);
        lo = __uint_as_float(r[0]); hi = __uint_as_float(r[1]);
    } else {
        auto r = __builtin_amdgcn_permlane32_swap(xu, xu, false, false);
        lo = __uint_as_float(r[0]); hi = __uint_as_float(r[1]);
    }
#else
    float d, s;
    if constexpr (B == 4)
        asm("v_mov_b32 %0, %2\n\tv_mov_b32 %1, %2\n\ts_nop 1\n\t"
            "v_permlane16_swap_b32 %0, %1"
            : "=&v"(d), "=&v"(s) : "v"(x));
    else
        asm("v_mov_b32 %0, %2\n\tv_mov_b32 %1, %2\n\ts_nop 1\n\t"
            "v_permlane32_swap_b32 %0, %1"
            : "=&v"(d), "=&v"(s) : "v"(x));
    lo = d; hi = s;
#endif
}

__device__ __forceinline__ float wave_sum(float v) {
    v += dppmov<0xB1>(v);    // xor1
    v += dppmov<0x4E>(v);    // xor2
    v += dppmov<0x141>(v);   // row_half_mirror = xor7 (bits 0-1 uniform)
    v += dppmov<0x140>(v);   // row_mirror = xor15 (bits 0-2 uniform)
    float lo, hi;
    swap2<4>(v, lo, hi); v = lo + hi;
    swap2<5>(v, lo, hi); v = lo + hi;
    return v;
}

// ---------- complex helpers (packed-math friendly) ----------

__device__ __forceinline__ f2 swapneg(f2 b) { f2 r; r.x = -b.y; r.y = b.x; return r; }
__device__ __forceinline__ f2 cmul(f2 a, f2 b) { return b * a.x + swapneg(b) * a.y; }
__device__ __forceinline__ f2 cfma(f2 a, f2 b, f2 acc) { return acc + b * a.x + swapneg(b) * a.y; }

// ---------- 1-qubit gate on index-bit B (wire w -> B = 9 - w) ----------

template<int B>
__device__ __forceinline__ void gate_bit(f2 (&v)[NREG], int lane,
                                         f2 g00, f2 g01, f2 g10, f2 g11) {
    if constexpr (B >= 6) {                       // register bit: pure in-reg
        constexpr int rb = B - 6;
#pragma unroll
        for (int p = 0; p < NREG / 2; ++p) {
            const int r0 = ((p >> rb) << (rb + 1)) | (p & ((1 << rb) - 1));
            const int r1 = r0 | (1 << rb);
            const f2 a0 = v[r0], a1 = v[r1];
            v[r0] = cfma(g01, a1, cmul(g00, a0));
            v[r1] = cfma(g11, a1, cmul(g10, a0));
        }
    } else if constexpr (B >= 4) {                // lane bit via permlane swap
        const bool hb = (lane >> B) & 1;
        const f2 A  = hb ? g10 : g00;             // coeff on lo value
        const f2 Bc = hb ? g11 : g01;             // coeff on hi value
#pragma unroll
        for (int r = 0; r < NREG; ++r) {
            float lx, hx, ly, hy;
            swap2<B>(v[r].x, lx, hx);
            swap2<B>(v[r].y, ly, hy);
            f2 lo; lo.x = lx; lo.y = ly;
            f2 hi; hi.x = hx; hi.y = hy;
            v[r] = cfma(Bc, hi, cmul(A, lo));
        }
    } else {                                      // lane bit via DPP
        const bool hb = (lane >> B) & 1;
        const f2 cO = hb ? g11 : g00;
        const f2 cP = hb ? g10 : g01;
#pragma unroll
        for (int r = 0; r < NREG; ++r) {
            f2 p;
            p.x = lxor<(1 << B)>(v[r].x, lane);
            p.y = lxor<(1 << B)>(v[r].y, lane);
            v[r] = cfma(cP, p, cmul(cO, v[r]));
        }
    }
}

// partner value x[l ^ (1<<BT)] for lane-resident target bit
template<int BT>
__device__ __forceinline__ float partner(float x, int lane) {
    if constexpr (BT >= 4) {
        float lo, hi; swap2<BT>(x, lo, hi);
        return ((lane >> BT) & 1) ? lo : hi;
    } else return lxor<(1 << BT)>(x, lane);
}

// ---------- CNOT ----------

template<int BC, int BT>
__device__ __forceinline__ void cnot(f2 (&v)[NREG], int lane) {
    if constexpr (BC >= 6 && BT >= 6) {           // both reg: free rename
        constexpr int rc = BC - 6, rt = BT - 6;
#pragma unroll
        for (int r = 0; r < NREG; ++r)
            if (((r >> rc) & 1) && !((r >> rt) & 1)) {
                const int r1 = r | (1 << rt);
                const f2 t = v[r]; v[r] = v[r1]; v[r1] = t;
            }
    } else if constexpr (BC >= 6) {               // reg control, lane target
        constexpr int rc = BC - 6;
#pragma unroll
        for (int r = 0; r < NREG; ++r)
            if ((r >> rc) & 1) {
                f2 n;
                n.x = partner<BT>(v[r].x, lane);
                n.y = partner<BT>(v[r].y, lane);
                v[r] = n;
            }
    } else if constexpr (BT >= 6) {               // lane control, reg target
        constexpr int rt = BT - 6;
        const bool c = (lane >> BC) & 1;
#pragma unroll
        for (int p = 0; p < NREG / 2; ++p) {
            const int r0 = ((p >> rt) << (rt + 1)) | (p & ((1 << rt) - 1));
            const int r1 = r0 | (1 << rt);
            const f2 a = v[r0], b = v[r1];
            v[r0] = c ? b : a;
            v[r1] = c ? a : b;
        }
    } else {                                      // both lane
        const bool c = (lane >> BC) & 1;
#pragma unroll
        for (int r = 0; r < NREG; ++r) {
            f2 n;
            n.x = c ? partner<BT>(v[r].x, lane) : v[r].x;
            n.y = c ? partner<BT>(v[r].y, lane) : v[r].y;
            v[r] = n;
        }
    }
}

// ---------- layer drivers (gates computed on the fly, wave-uniform VGPRs) ----------

template<int L, int Q = 0>
__device__ __forceinline__ void rot_layer_otf(f2 (&v)[NREG], int lane,
                                              const float* __restrict__ wts) {
    if constexpr (Q < NQ) {
        const float phi = wts[(L * NQ + Q) * 3 + 0];   // uniform -> s_load
        const float th  = wts[(L * NQ + Q) * 3 + 1];
        const float om  = wts[(L * NQ + Q) * 3 + 2];
        float st, ct, sA, cA, sB, cB;
        __sincosf(0.5f * th, &st, &ct);
        __sincosf(0.5f * (phi + om), &sA, &cA);
        __sincosf(0.5f * (phi - om), &sB, &cB);
        f2 g00 = { ct * cA, -ct * sA};
        f2 g01 = {-st * cB, -st * sB};
        f2 g10 = { st * cB, -st * sB};
        f2 g11 = { ct * cA,  ct * sA};
        gate_bit<9 - Q>(v, lane, g00, g01, g10, g11);
        rot_layer_otf<L, Q + 1>(v, lane, wts);
    }
}

template<int L, int I = 0>
__device__ __forceinline__ void cnot_ring(f2 (&v)[NREG], int lane) {
    if constexpr (I < NQ) {
        constexpr int R = (L % (NQ - 1)) + 1;
        cnot<9 - I, 9 - ((I + R) % NQ)>(v, lane);
        cnot_ring<L, I + 1>(v, lane);
    }
}

// ---------- ring-2 absorbed measurement ----------
constexpr unsigned ring2_mask(int w) {
    unsigned M[NQ] = {};
    for (int i = 0; i < NQ; ++i) M[i] = 1u << (9 - i);
    for (int i = 0; i < NQ; ++i) M[(i + 3) % NQ] ^= M[i];
    return M[w];
}

template<unsigned MR>
__device__ __forceinline__ float regsum16(const float (&pr)[NREG]) {
    float s = 0.f;
#pragma unroll
    for (int r = 0; r < NREG; ++r)
        s = (__builtin_popcount((unsigned)r & MR) & 1) ? s - pr[r] : s + pr[r];
    return s;
}

template<int W = 0>
__device__ __forceinline__ void measure_all(const float (&pr)[NREG], int lane,
                                            float (&ev)[NQ]) {
    if constexpr (W < NQ) {
        constexpr unsigned m  = ring2_mask(W);
        constexpr unsigned mr = (m >> 6) & 0xFu;   // register-bit part
        constexpr unsigned ml = m & 63u;           // lane-bit part
        float s = regsum16<mr>(pr);
        if constexpr (ml != 0) {
            const unsigned flip = (unsigned)((__popc(lane & (int)ml) & 1)) << 31;
            s = __uint_as_float(__float_as_uint(s) ^ flip);
        }
        ev[W] = wave_sum(s);
        measure_all<W + 1>(pr, lane, ev);
    }
}

// ---------- circuit kernel: input GEMM + circuit + evs ----------
__global__ __launch_bounds__(64 * WPB, 2) void qcirc(
    const float* __restrict__ z,     // (B, CDIM)
    const float* __restrict__ Win,   // (CDIM, NQ)
    const float* __restrict__ bin,   // (NQ)
    const float* __restrict__ wts,   // (NL, NQ, 3)
    float* __restrict__ evs)         // (B, NQ) workspace
{
    const int wave = threadIdx.x >> 6;
    const int lane = threadIdx.x & 63;
    const int samp = blockIdx.x * WPB + wave;

    // ---- angles = z[samp] @ Win + bin (z batched first) ----
    float ang[NQ];
    {
        const float* zrow = z + (size_t)samp * CDIM;
        float zr[CDIM / 64];
#pragma unroll
        for (int j = 0; j < CDIM / 64; ++j) zr[j] = zrow[lane + j * 64];

        float acc[NQ];
#pragma unroll
        for (int q = 0; q < NQ; ++q) acc[q] = 0.f;
#pragma unroll
        for (int j = 0; j < CDIM / 64; ++j) {
            const int k = lane + j * 64;
            const f2* wr = (const f2*)(Win + k * NQ);   // 8B-aligned (k*10 even)
#pragma unroll
            for (int h = 0; h < NQ / 2; ++h) {
                const f2 w = wr[h];
                acc[2 * h]     += zr[j] * w.x;
                acc[2 * h + 1] += zr[j] * w.y;
            }
        }
#pragma unroll
        for (int q = 0; q < NQ; ++q) ang[q] = wave_sum(acc[q]) + bin[q];
    }

    // ---- layer 0 on |0..0>: product state built directly ----
    f2 f0[NQ], f1[NQ];
#pragma unroll
    for (int q = 0; q < NQ; ++q) {
        const float phi = wts[q * 3 + 0];   // uniform -> s_load
        const float th  = wts[q * 3 + 1];
        const float om  = wts[q * 3 + 2];
        float st, ct, sA, cA, sB, cB, s, c;
        __sincosf(0.5f * th, &st, &ct);
        __sincosf(0.5f * (phi + om), &sA, &cA);
        __sincosf(0.5f * (phi - om), &sB, &cB);
        __sincosf(0.5f * ang[q], &s, &c);
        const float g00x =  ct * cA, g00y = -ct * sA;
        const float g01x = -st * cB, g01y = -st * sB;
        const float g10x =  st * cB, g10y = -st * sB;
        const float g11x =  ct * cA, g11y =  ct * sA;
        f2 a, b;
        a.x = g00x * c + s * g01y;  a.y = g00y * c - s * g01x;
        b.x = g10x * c + s * g11y;  b.y = g10y * c - s * g11x;
        f0[q] = a; f1[q] = b;
    }
    // lane-bit factors: bit b (0..5) <-> wire 9-b
    f2 s0 = ((lane >> 0) & 1) ? f1[9] : f0[9];
    f2 s1 = ((lane >> 1) & 1) ? f1[8] : f0[8];
    f2 s2 = ((lane >> 2) & 1) ? f1[7] : f0[7];
    f2 s3 = ((lane >> 3) & 1) ? f1[6] : f0[6];
    f2 s4 = ((lane >> 4) & 1) ? f1[5] : f0[5];
    f2 s5 = ((lane >> 5) & 1) ? f1[4] : f0[4];
    const f2 L = cmul(cmul(cmul(s0, s1), cmul(s2, s3)), cmul(s4, s5));

    f2 LT[4], U2[4];
#pragma unroll
    for (int j = 0; j < 4; ++j) {
        const f2 t = cmul((j & 1) ? f1[3] : f0[3], (j & 2) ? f1[2] : f0[2]);
        LT[j] = cmul(L, t);
        U2[j] = cmul((j & 1) ? f1[1] : f0[1], (j & 2) ? f1[0] : f0[0]);
    }
    f2 v[NREG];
#pragma unroll
    for (int r = 0; r < NREG; ++r) v[r] = cmul(LT[r & 3], U2[r >> 2]);

    // ---- remaining circuit (ring 2 absorbed into measurement) ----
    cnot_ring<0>(v, lane);
    rot_layer_otf<1>(v, lane, wts);  cnot_ring<1>(v, lane);
    rot_layer_otf<2>(v, lane, wts);

    // ---- expectation values with ring-2 parity masks ----
    float pr[NREG];
#pragma unroll
    for (int r = 0; r < NREG; ++r) pr[r] = v[r].x * v[r].x + v[r].y * v[r].y;

    float ev[NQ];
    measure_all(pr, lane, ev);

    if (lane == 0) {
#pragma unroll
        for (int w = 0; w < NQ; ++w) evs[(size_t)samp * NQ + w] = ev[w];
    }
}

// ---------- output GEMM: out = evs @ Wout + bout ----------
constexpr int SPB = 16;   // samples per block
constexpr int DCH = CDIM / 256;   // 3 column chunks

__global__ __launch_bounds__(256) void gemm_out(
    const float* __restrict__ evs,   // (B, NQ)
    const float* __restrict__ Wout,  // (NQ, CDIM)
    const float* __restrict__ bout,  // (CDIM)
    float* __restrict__ out)         // (B, CDIM)
{
    const int dchunk = blockIdx.x % DCH;
    const int s0     = (blockIdx.x / DCH) * SPB;
    const int d      = dchunk * 256 + threadIdx.x;

    float wr[NQ];
#pragma unroll
    for (int q = 0; q < NQ; ++q) wr[q] = Wout[q * CDIM + d];
    const float bo = bout[d];

#pragma unroll
    for (int s = 0; s < SPB; ++s) {
        const int samp = s0 + s;
        float o = bo;
#pragma unroll
        for (int q = 0; q < NQ; ++q) o += evs[(size_t)samp * NQ + q] * wr[q];
        out[(size_t)samp * CDIM + d] = o;
    }
}

extern "C" void kernel_launch(void* const* d_in, const int* in_sizes, int n_in,
                              void* d_out, int out_size, void* d_ws, size_t ws_size,
                              hipStream_t stream) {
    const float* z    = (const float*)d_in[0];
    const float* Win  = (const float*)d_in[1];
    const float* bin  = (const float*)d_in[2];
    const float* wts  = (const float*)d_in[3];
    const float* Wout = (const float*)d_in[4];
    const float* bout = (const float*)d_in[5];
    float* outp       = (float*)d_out;
    float* evs        = (float*)d_ws;        // batch * NQ floats = 80 KB

    const int batch = in_sizes[0] / CDIM;    // 2048
    qcirc<<<batch / WPB, 64 * WPB, 0, stream>>>(z, Win, bin, wts, evs);
    gemm_out<<<DCH * (batch / SPB), 256, 0, stream>>>(evs, Wout, bout, outp);
}

// Round 11
// 29.038 us; speedup vs baseline: 1.1915x; 1.1915x over previous
//
#include <hip/hip_runtime.h>

typedef float f2 __attribute__((ext_vector_type(2)));   // complex (re, im)

constexpr int NQ   = 10;
constexpr int CDIM = 768;
constexpr int NL   = 3;
constexpr int NREG = 16;   // index bits 6..9 in the register index
constexpr int WPB  = 4;    // waves (= samples) per block

// ---------- cross-lane primitives (all VALU, no LDS pipe) ----------

template<int CTRL>
__device__ __forceinline__ float dppmov(float x) {
    return __int_as_float(__builtin_amdgcn_update_dpp(
        __float_as_int(x), __float_as_int(x), CTRL, 0xF, 0xF, true));
}

// y[l] = x[l ^ MASK] for MASK in {1,2,4,8}
template<int MASK>
__device__ __forceinline__ float lxor(float x, int lane) {
    static_assert(MASK == 1 || MASK == 2 || MASK == 4 || MASK == 8, "");
    if constexpr (MASK == 1)      return dppmov<0xB1>(x);   // quad_perm [1,0,3,2]
    else if constexpr (MASK == 2) return dppmov<0x4E>(x);   // quad_perm [2,3,0,1]
    else if constexpr (MASK == 4) {
        const float a = dppmov<0x104>(x);   // row_shl:4 -> src[i+4] (bit2=0 lanes)
        const float b = dppmov<0x114>(x);   // row_shr:4 -> src[i-4] (bit2=1 lanes)
        return ((lane >> 2) & 1) ? b : a;
    }
    else                          return dppmov<0x128>(x);  // row_ror:8 == xor8
}

// B in {4,5}: lo = x[l & ~(1<<B)], hi = x[l | (1<<B)]  (one swap instr)
template<int B>
__device__ __forceinline__ void swap2(float x, float& lo, float& hi) {
    const unsigned xu = __float_as_uint(x);
#if __has_builtin(__builtin_amdgcn_permlane16_swap) && __has_builtin(__builtin_amdgcn_permlane32_swap)
    if constexpr (B == 4) {
        auto r = __builtin_amdgcn_permlane16_swap(xu, xu, false, false);
        lo = __uint_as_float(r[0]); hi = __uint_as_float(r[1]);
    } else {
        auto r = __builtin_amdgcn_permlane32_swap(xu, xu, false, false);
        lo = __uint_as_float(r[0]); hi = __uint_as_float(r[1]);
    }
#else
    float d, s;
    if constexpr (B == 4)
        asm("v_mov_b32 %0, %2\n\tv_mov_b32 %1, %2\n\ts_nop 1\n\t"
            "v_permlane16_swap_b32 %0, %1"
            : "=&v"(d), "=&v"(s) : "v"(x));
    else
        asm("v_mov_b32 %0, %2\n\tv_mov_b32 %1, %2\n\ts_nop 1\n\t"
            "v_permlane32_swap_b32 %0, %1"
            : "=&v"(d), "=&v"(s) : "v"(x));
    lo = d; hi = s;
#endif
}

__device__ __forceinline__ float wave_sum(float v) {
    v += dppmov<0xB1>(v);    // xor1
    v += dppmov<0x4E>(v);    // xor2
    v += dppmov<0x141>(v);   // row_half_mirror = xor7 (bits 0-1 uniform)
    v += dppmov<0x140>(v);   // row_mirror = xor15 (bits 0-2 uniform)
    float lo, hi;
    swap2<4>(v, lo, hi); v = lo + hi;
    swap2<5>(v, lo, hi); v = lo + hi;
    return v;
}

// ---------- complex helpers (packed-math friendly) ----------

__device__ __forceinline__ f2 swapneg(f2 b) { f2 r; r.x = -b.y; r.y = b.x; return r; }
__device__ __forceinline__ f2 cmul(f2 a, f2 b) { return b * a.x + swapneg(b) * a.y; }
__device__ __forceinline__ f2 cfma(f2 a, f2 b, f2 acc) { return acc + b * a.x + swapneg(b) * a.y; }

// ---------- 1-qubit gate on index-bit B (wire w -> B = 9 - w) ----------

template<int B>
__device__ __forceinline__ void gate_bit(f2 (&v)[NREG], int lane,
                                         f2 g00, f2 g01, f2 g10, f2 g11) {
    if constexpr (B >= 6) {                       // register bit: pure in-reg
        constexpr int rb = B - 6;
#pragma unroll
        for (int p = 0; p < NREG / 2; ++p) {
            const int r0 = ((p >> rb) << (rb + 1)) | (p & ((1 << rb) - 1));
            const int r1 = r0 | (1 << rb);
            const f2 a0 = v[r0], a1 = v[r1];
            v[r0] = cfma(g01, a1, cmul(g00, a0));
            v[r1] = cfma(g11, a1, cmul(g10, a0));
        }
    } else if constexpr (B >= 4) {                // lane bit via permlane swap
        const bool hb = (lane >> B) & 1;
        const f2 A  = hb ? g10 : g00;             // coeff on lo value
        const f2 Bc = hb ? g11 : g01;             // coeff on hi value
#pragma unroll
        for (int r = 0; r < NREG; ++r) {
            float lx, hx, ly, hy;
            swap2<B>(v[r].x, lx, hx);
            swap2<B>(v[r].y, ly, hy);
            f2 lo; lo.x = lx; lo.y = ly;
            f2 hi; hi.x = hx; hi.y = hy;
            v[r] = cfma(Bc, hi, cmul(A, lo));
        }
    } else {                                      // lane bit via DPP
        const bool hb = (lane >> B) & 1;
        const f2 cO = hb ? g11 : g00;
        const f2 cP = hb ? g10 : g01;
#pragma unroll
        for (int r = 0; r < NREG; ++r) {
            f2 p;
            p.x = lxor<(1 << B)>(v[r].x, lane);
            p.y = lxor<(1 << B)>(v[r].y, lane);
            v[r] = cfma(cP, p, cmul(cO, v[r]));
        }
    }
}

// partner value x[l ^ (1<<BT)] for lane-resident target bit
template<int BT>
__device__ __forceinline__ float partner(float x, int lane) {
    if constexpr (BT >= 4) {
        float lo, hi; swap2<BT>(x, lo, hi);
        return ((lane >> BT) & 1) ? lo : hi;
    } else return lxor<(1 << BT)>(x, lane);
}

// ---------- CNOT ----------

template<int BC, int BT>
__device__ __forceinline__ void cnot(f2 (&v)[NREG], int lane) {
    if constexpr (BC >= 6 && BT >= 6) {           // both reg: free rename
        constexpr int rc = BC - 6, rt = BT - 6;
#pragma unroll
        for (int r = 0; r < NREG; ++r)
            if (((r >> rc) & 1) && !((r >> rt) & 1)) {
                const int r1 = r | (1 << rt);
                const f2 t = v[r]; v[r] = v[r1]; v[r1] = t;
            }
    } else if constexpr (BC >= 6) {               // reg control, lane target
        constexpr int rc = BC - 6;
#pragma unroll
        for (int r = 0; r < NREG; ++r)
            if ((r >> rc) & 1) {
                f2 n;
                n.x = partner<BT>(v[r].x, lane);
                n.y = partner<BT>(v[r].y, lane);
                v[r] = n;
            }
    } else if constexpr (BT >= 6) {               // lane control, reg target
        constexpr int rt = BT - 6;
        const bool c = (lane >> BC) & 1;
#pragma unroll
        for (int p = 0; p < NREG / 2; ++p) {
            const int r0 = ((p >> rt) << (rt + 1)) | (p & ((1 << rt) - 1));
            const int r1 = r0 | (1 << rt);
            const f2 a = v[r0], b = v[r1];
            v[r0] = c ? b : a;
            v[r1] = c ? a : b;
        }
    } else {                                      // both lane
        const bool c = (lane >> BC) & 1;
#pragma unroll
        for (int r = 0; r < NREG; ++r) {
            f2 n;
            n.x = c ? partner<BT>(v[r].x, lane) : v[r].x;
            n.y = c ? partner<BT>(v[r].y, lane) : v[r].y;
            v[r] = n;
        }
    }
}

// ---------- rot layer: runtime base pointer (code emitted ONCE, looped) ----------

template<int Q = 0>
__device__ __forceinline__ void rot_layer_q(f2 (&v)[NREG], int lane,
                                            const float* __restrict__ w30) {
    if constexpr (Q < NQ) {
        const float phi = w30[Q * 3 + 0];   // uniform -> s_load
        const float th  = w30[Q * 3 + 1];
        const float om  = w30[Q * 3 + 2];
        float st, ct, sA, cA, sB, cB;
        __sincosf(0.5f * th, &st, &ct);
        __sincosf(0.5f * (phi + om), &sA, &cA);
        __sincosf(0.5f * (phi - om), &sB, &cB);
        f2 g00 = { ct * cA, -ct * sA};
        f2 g01 = {-st * cB, -st * sB};
        f2 g10 = { st * cB, -st * sB};
        f2 g11 = { ct * cA,  ct * sA};
        gate_bit<9 - Q>(v, lane, g00, g01, g10, g11);
        rot_layer_q<Q + 1>(v, lane, w30);
    }
}

template<int L, int I = 0>
__device__ __forceinline__ void cnot_ring(f2 (&v)[NREG], int lane) {
    if constexpr (I < NQ) {
        constexpr int R = (L % (NQ - 1)) + 1;
        cnot<9 - I, 9 - ((I + R) % NQ)>(v, lane);
        cnot_ring<L, I + 1>(v, lane);
    }
}

// ---------- ring-2 absorbed measurement ----------
constexpr unsigned ring2_mask(int w) {
    unsigned M[NQ] = {};
    for (int i = 0; i < NQ; ++i) M[i] = 1u << (9 - i);
    for (int i = 0; i < NQ; ++i) M[(i + 3) % NQ] ^= M[i];
    return M[w];
}

template<unsigned MR>
__device__ __forceinline__ float regsum16(const float (&pr)[NREG]) {
    float s = 0.f;
#pragma unroll
    for (int r = 0; r < NREG; ++r)
        s = (__builtin_popcount((unsigned)r & MR) & 1) ? s - pr[r] : s + pr[r];
    return s;
}

template<int W = 0>
__device__ __forceinline__ void measure_all(const float (&pr)[NREG], int lane,
                                            float (&ev)[NQ]) {
    if constexpr (W < NQ) {
        constexpr unsigned m  = ring2_mask(W);
        constexpr unsigned mr = (m >> 6) & 0xFu;   // register-bit part
        constexpr unsigned ml = m & 63u;           // lane-bit part
        float s = regsum16<mr>(pr);
        if constexpr (ml != 0) {
            const unsigned flip = (unsigned)((__popc(lane & (int)ml) & 1)) << 31;
            s = __uint_as_float(__float_as_uint(s) ^ flip);
        }
        ev[W] = wave_sum(s);
        measure_all<W + 1>(pr, lane, ev);
    }
}

// ---------- main kernel (single launch) ----------
// (256, 2): grid is capped at 2048 waves = 2/SIMD anyway -> allow 256 VGPRs
__global__ __launch_bounds__(64 * WPB, 2) void qembed(
    const float* __restrict__ z,     // (B, CDIM)
    const float* __restrict__ Win,   // (CDIM, NQ)
    const float* __restrict__ bin,   // (NQ)
    const float* __restrict__ wts,   // (NL, NQ, 3)
    const float* __restrict__ Wout,  // (NQ, CDIM)
    const float* __restrict__ bout,  // (CDIM)
    float* __restrict__ out)         // (B, CDIM)
{
    const int wave = threadIdx.x >> 6;
    const int lane = threadIdx.x & 63;
    const int samp = blockIdx.x * WPB + wave;

    // ---- angles = z[samp] @ Win + bin (z batched, packed acc) ----
    float ang[NQ];
    {
        const float* zrow = z + (size_t)samp * CDIM;
        float zr[CDIM / 64];
#pragma unroll
        for (int j = 0; j < CDIM / 64; ++j) zr[j] = zrow[lane + j * 64];

        f2 a5[NQ / 2];
#pragma unroll
        for (int h = 0; h < NQ / 2; ++h) a5[h] = (f2){0.f, 0.f};
#pragma unroll
        for (int j = 0; j < CDIM / 64; ++j) {
            const int k = lane + j * 64;
            const f2* wr = (const f2*)(Win + k * NQ);   // 8B-aligned (k*10 even)
#pragma unroll
            for (int h = 0; h < NQ / 2; ++h) a5[h] += wr[h] * zr[j];
        }
#pragma unroll
        for (int h = 0; h < NQ / 2; ++h) {
            ang[2 * h]     = wave_sum(a5[h].x) + bin[2 * h];
            ang[2 * h + 1] = wave_sum(a5[h].y) + bin[2 * h + 1];
        }
    }

    // ---- fused layer-0 gate first columns: F_q = Rot(l0,q)*RX(ang_q) ----
    f2 f0[NQ], f1[NQ];
#pragma unroll
    for (int q = 0; q < NQ; ++q) {
        const float phi = wts[q * 3 + 0];   // uniform -> s_load
        const float th  = wts[q * 3 + 1];
        const float om  = wts[q * 3 + 2];
        float st, ct, sA, cA, sB, cB, s, c;
        __sincosf(0.5f * th, &st, &ct);
        __sincosf(0.5f * (phi + om), &sA, &cA);
        __sincosf(0.5f * (phi - om), &sB, &cB);
        __sincosf(0.5f * ang[q], &s, &c);
        const float g00x =  ct * cA, g00y = -ct * sA;
        const float g01x = -st * cB, g01y = -st * sB;
        const float g10x =  st * cB, g10y = -st * sB;
        const float g11x =  ct * cA, g11y =  ct * sA;
        f2 a, b;
        a.x = g00x * c + s * g01y;  a.y = g00y * c - s * g01x;
        b.x = g10x * c + s * g11y;  b.y = g10y * c - s * g11x;
        f0[q] = a; f1[q] = b;
    }

    // ---- product state built POST-ring-0 (ring 0 absorbed) ----
    // Ring-0 inverse: x_j = y_j^y_{j+1} (j=0..7), x8 = y0^y8^y9, x9 = y0^y9.
    // y bits: 0..5 = lane bits, 6..9 = reg bits r0..r3. Wire w <-> orig bit 9-w.
    const int gray = lane ^ (lane >> 1);
    const int l0 = lane & 1;
    const int l5 = (lane >> 5) & 1;
    // orig bits j=0..4 (wires 9..5): lane-only selections
    f2 G0 = ((gray >> 0) & 1) ? f1[9] : f0[9];
    f2 G1 = ((gray >> 1) & 1) ? f1[8] : f0[8];
    f2 G2 = ((gray >> 2) & 1) ? f1[7] : f0[7];
    f2 G3 = ((gray >> 3) & 1) ? f1[6] : f0[6];
    f2 G4 = ((gray >> 4) & 1) ? f1[5] : f0[5];
    const f2 L5 = cmul(cmul(G0, G1), cmul(G2, cmul(G3, G4)));
    // orig bit 5 (wire 4): t = lane5 ^ r0
    f2 B5[2];
    B5[0] = l5 ? f1[4] : f0[4];
    B5[1] = l5 ? f0[4] : f1[4];
    // orig bit 8 (wire 1): t = lane0 ^ r2 ^ r3 ; orig bit 9 (wire 0): t = lane0 ^ r3
    f2 D8[2], E9[2];
    D8[0] = l0 ? f1[1] : f0[1];
    D8[1] = l0 ? f0[1] : f1[1];
    E9[0] = l0 ? f1[0] : f0[0];
    E9[1] = l0 ? f0[0] : f1[0];

    f2 P1[2];
    P1[0] = cmul(L5, B5[0]);
    P1[1] = cmul(L5, B5[1]);
    f2 P2[4];   // index r0 + 2*r1; orig bit 6 (wire 3): t = r0^r1
#pragma unroll
    for (int r1b = 0; r1b < 2; ++r1b)
#pragma unroll
        for (int r0b = 0; r0b < 2; ++r0b)
            P2[r0b + 2 * r1b] = cmul(P1[r0b], (r0b ^ r1b) ? f1[3] : f0[3]);
    f2 P3[8];   // index r0 + 2*r1 + 4*r2; orig bit 7 (wire 2): t = r1^r2
#pragma unroll
    for (int r2b = 0; r2b < 2; ++r2b)
#pragma unroll
        for (int p = 0; p < 4; ++p)
            P3[p + 4 * r2b] = cmul(P2[p], (((p >> 1) & 1) ^ r2b) ? f1[2] : f0[2]);
    f2 W[4];    // index (r2^r3) + 2*r3
#pragma unroll
    for (int d = 0; d < 2; ++d)
#pragma unroll
        for (int u = 0; u < 2; ++u)
            W[u + 2 * d] = cmul(D8[u], E9[d]);

    f2 v[NREG];
#pragma unroll
    for (int r = 0; r < NREG; ++r) {
        const int r2b = (r >> 2) & 1, r3b = (r >> 3) & 1;
        v[r] = cmul(P3[r & 7], W[(r2b ^ r3b) + 2 * r3b]);
    }

    // ---- layers 1..2: looped (code emitted once); ring 2 absorbed ----
#pragma unroll 1
    for (int l = 1; l < NL; ++l) {
        rot_layer_q(v, lane, wts + l * NQ * 3);
        if (l == 1) cnot_ring<1>(v, lane);
    }

    // ---- expectation values with ring-2 parity masks ----
    float pr[NREG];
#pragma unroll
    for (int r = 0; r < NREG; ++r) pr[r] = v[r].x * v[r].x + v[r].y * v[r].y;

    float ev[NQ];
    measure_all(pr, lane, ev);

    // ---- out[samp] = ev @ Wout + bout (load-all-then-FMA halves) ----
#pragma unroll
    for (int half = 0; half < 2; ++half) {
        float wr[6][NQ];
        float bo[6];
#pragma unroll
        for (int j = 0; j < 6; ++j) {
            const int d = lane + (half * 6 + j) * 64;
            bo[j] = bout[d];
#pragma unroll
            for (int q = 0; q < NQ; ++q) wr[j][q] = Wout[q * CDIM + d];
        }
#pragma unroll
        for (int j = 0; j < 6; ++j) {
            const int d = lane + (half * 6 + j) * 64;
            float o = bo[j];
#pragma unroll
            for (int q = 0; q < NQ; ++q) o += ev[q] * wr[j][q];
            out[(size_t)samp * CDIM + d] = o;
        }
    }
}

extern "C" void kernel_launch(void* const* d_in, const int* in_sizes, int n_in,
                              void* d_out, int out_size, void* d_ws, size_t ws_size,
                              hipStream_t stream) {
    const float* z    = (const float*)d_in[0];
    const float* Win  = (const float*)d_in[1];
    const float* bin  = (const float*)d_in[2];
    const float* wts  = (const float*)d_in[3];
    const float* Wout = (const float*)d_in[4];
    const float* bout = (const float*)d_in[5];
    float* outp       = (float*)d_out;

    const int batch  = in_sizes[0] / CDIM;   // 2048
    const int blocks = batch / WPB;          // 512
    qembed<<<blocks, 64 * WPB, 0, stream>>>(z, Win, bin, wts, Wout, bout, outp);
}

// Round 12
// 27.447 us; speedup vs baseline: 1.2605x; 1.0580x over previous
//
#include <hip/hip_runtime.h>

typedef float f2 __attribute__((ext_vector_type(2)));   // complex (re, im)

constexpr int NQ   = 10;
constexpr int CDIM = 768;
constexpr int NL   = 3;
constexpr int NREG = 16;   // index bits 6..9 in the register index
constexpr int WPB  = 4;    // waves (= samples) per block

// ---------- cross-lane primitives (all VALU, no LDS pipe) ----------

template<int CTRL>
__device__ __forceinline__ float dppmov(float x) {
    return __int_as_float(__builtin_amdgcn_update_dpp(
        __float_as_int(x), __float_as_int(x), CTRL, 0xF, 0xF, true));
}

// y[l] = x[l ^ MASK] for MASK in {1,2,4,8}
template<int MASK>
__device__ __forceinline__ float lxor(float x, int lane) {
    static_assert(MASK == 1 || MASK == 2 || MASK == 4 || MASK == 8, "");
    if constexpr (MASK == 1)      return dppmov<0xB1>(x);   // quad_perm [1,0,3,2]
    else if constexpr (MASK == 2) return dppmov<0x4E>(x);   // quad_perm [2,3,0,1]
    else if constexpr (MASK == 4) {
        const float a = dppmov<0x104>(x);   // row_shl:4 -> src[i+4] (bit2=0 lanes)
        const float b = dppmov<0x114>(x);   // row_shr:4 -> src[i-4] (bit2=1 lanes)
        return ((lane >> 2) & 1) ? b : a;
    }
    else                          return dppmov<0x128>(x);  // row_ror:8 == xor8
}

// B in {4,5}: lo = x[l & ~(1<<B)], hi = x[l | (1<<B)]  (one swap instr)
template<int B>
__device__ __forceinline__ void swap2(float x, float& lo, float& hi) {
    const unsigned xu = __float_as_uint(x);
#if __has_builtin(__builtin_amdgcn_permlane16_swap) && __has_builtin(__builtin_amdgcn_permlane32_swap)
    if constexpr (B == 4) {
        auto r = __builtin_amdgcn_permlane16_swap(xu, xu, false, false);
        lo = __uint_as_float(r[0]); hi = __uint_as_float(r[1]);
    } else {
        auto r = __builtin_amdgcn_permlane32_swap(xu, xu, false, false);
        lo = __uint_as_float(r[0]); hi = __uint_as_float(r[1]);
    }
#else
    float d, s;
    if constexpr (B == 4)
        asm("v_mov_b32 %0, %2\n\tv_mov_b32 %1, %2\n\ts_nop 1\n\t"
            "v_permlane16_swap_b32 %0, %1"
            : "=&v"(d), "=&v"(s) : "v"(x));
    else
        asm("v_mov_b32 %0, %2\n\tv_mov_b32 %1, %2\n\ts_nop 1\n\t"
            "v_permlane32_swap_b32 %0, %1"
            : "=&v"(d), "=&v"(s) : "v"(x));
    lo = d; hi = s;
#endif
}

__device__ __forceinline__ float wave_sum(float v) {
    v += dppmov<0xB1>(v);    // xor1
    v += dppmov<0x4E>(v);    // xor2
    v += dppmov<0x141>(v);   // row_half_mirror = xor7 (bits 0-1 uniform)
    v += dppmov<0x140>(v);   // row_mirror = xor15 (bits 0-2 uniform)
    float lo, hi;
    swap2<4>(v, lo, hi); v = lo + hi;
    swap2<5>(v, lo, hi); v = lo + hi;
    return v;
}

// ---------- complex helpers (packed-math friendly) ----------

__device__ __forceinline__ f2 swapneg(f2 b) { f2 r; r.x = -b.y; r.y = b.x; return r; }
__device__ __forceinline__ f2 cmul(f2 a, f2 b) { return b * a.x + swapneg(b) * a.y; }
__device__ __forceinline__ f2 cfma(f2 a, f2 b, f2 acc) { return acc + b * a.x + swapneg(b) * a.y; }

// ---------- 1-qubit gate on index-bit B (wire w -> B = 9 - w) ----------

template<int B>
__device__ __forceinline__ void gate_bit(f2 (&v)[NREG], int lane,
                                         f2 g00, f2 g01, f2 g10, f2 g11) {
    if constexpr (B >= 6) {                       // register bit: pure in-reg
        constexpr int rb = B - 6;
#pragma unroll
        for (int p = 0; p < NREG / 2; ++p) {
            const int r0 = ((p >> rb) << (rb + 1)) | (p & ((1 << rb) - 1));
            const int r1 = r0 | (1 << rb);
            const f2 a0 = v[r0], a1 = v[r1];
            v[r0] = cfma(g01, a1, cmul(g00, a0));
            v[r1] = cfma(g11, a1, cmul(g10, a0));
        }
    } else if constexpr (B >= 4) {                // lane bit via permlane swap
        const bool hb = (lane >> B) & 1;
        const f2 A  = hb ? g10 : g00;             // coeff on lo value
        const f2 Bc = hb ? g11 : g01;             // coeff on hi value
#pragma unroll
        for (int r = 0; r < NREG; ++r) {
            float lx, hx, ly, hy;
            swap2<B>(v[r].x, lx, hx);
            swap2<B>(v[r].y, ly, hy);
            f2 lo; lo.x = lx; lo.y = ly;
            f2 hi; hi.x = hx; hi.y = hy;
            v[r] = cfma(Bc, hi, cmul(A, lo));
        }
    } else {                                      // lane bit via DPP
        const bool hb = (lane >> B) & 1;
        const f2 cO = hb ? g11 : g00;
        const f2 cP = hb ? g10 : g01;
#pragma unroll
        for (int r = 0; r < NREG; ++r) {
            f2 p;
            p.x = lxor<(1 << B)>(v[r].x, lane);
            p.y = lxor<(1 << B)>(v[r].y, lane);
            v[r] = cfma(cP, p, cmul(cO, v[r]));
        }
    }
}

// partner value x[l ^ (1<<BT)] for lane-resident target bit
template<int BT>
__device__ __forceinline__ float partner(float x, int lane) {
    if constexpr (BT >= 4) {
        float lo, hi; swap2<BT>(x, lo, hi);
        return ((lane >> BT) & 1) ? lo : hi;
    } else return lxor<(1 << BT)>(x, lane);
}

// ---------- CNOT ----------

template<int BC, int BT>
__device__ __forceinline__ void cnot(f2 (&v)[NREG], int lane) {
    if constexpr (BC >= 6 && BT >= 6) {           // both reg: free rename
        constexpr int rc = BC - 6, rt = BT - 6;
#pragma unroll
        for (int r = 0; r < NREG; ++r)
            if (((r >> rc) & 1) && !((r >> rt) & 1)) {
                const int r1 = r | (1 << rt);
                const f2 t = v[r]; v[r] = v[r1]; v[r1] = t;
            }
    } else if constexpr (BC >= 6) {               // reg control, lane target
        constexpr int rc = BC - 6;
#pragma unroll
        for (int r = 0; r < NREG; ++r)
            if ((r >> rc) & 1) {
                f2 n;
                n.x = partner<BT>(v[r].x, lane);
                n.y = partner<BT>(v[r].y, lane);
                v[r] = n;
            }
    } else if constexpr (BT >= 6) {               // lane control, reg target
        constexpr int rt = BT - 6;
        const bool c = (lane >> BC) & 1;
#pragma unroll
        for (int p = 0; p < NREG / 2; ++p) {
            const int r0 = ((p >> rt) << (rt + 1)) | (p & ((1 << rt) - 1));
            const int r1 = r0 | (1 << rt);
            const f2 a = v[r0], b = v[r1];
            v[r0] = c ? b : a;
            v[r1] = c ? a : b;
        }
    } else {                                      // both lane
        const bool c = (lane >> BC) & 1;
#pragma unroll
        for (int r = 0; r < NREG; ++r) {
            f2 n;
            n.x = c ? partner<BT>(v[r].x, lane) : v[r].x;
            n.y = c ? partner<BT>(v[r].y, lane) : v[r].y;
            v[r] = n;
        }
    }
}

// ---------- rot layer from LDS matrices (code emitted ONCE, looped) ----------

template<int Q = 0>
__device__ __forceinline__ void rot_layer_lds(f2 (&v)[NREG], int lane,
                                              const float4* g /*LDS, [NQ][2]*/) {
    if constexpr (Q < NQ) {
        const float4 p0 = g[Q * 2];        // broadcast ds_read_b128
        const float4 p1 = g[Q * 2 + 1];
        f2 g00 = {p0.x, p0.y}, g01 = {p0.z, p0.w};
        f2 g10 = {p1.x, p1.y}, g11 = {p1.z, p1.w};
        gate_bit<9 - Q>(v, lane, g00, g01, g10, g11);
        rot_layer_lds<Q + 1>(v, lane, g);
    }
}

template<int L, int I = 0>
__device__ __forceinline__ void cnot_ring(f2 (&v)[NREG], int lane) {
    if constexpr (I < NQ) {
        constexpr int R = (L % (NQ - 1)) + 1;
        cnot<9 - I, 9 - ((I + R) % NQ)>(v, lane);
        cnot_ring<L, I + 1>(v, lane);
    }
}

// ---------- ring-2 absorbed measurement ----------
constexpr unsigned ring2_mask(int w) {
    unsigned M[NQ] = {};
    for (int i = 0; i < NQ; ++i) M[i] = 1u << (9 - i);
    for (int i = 0; i < NQ; ++i) M[(i + 3) % NQ] ^= M[i];
    return M[w];
}

template<unsigned MR>
__device__ __forceinline__ float regsum16(const float (&pr)[NREG]) {
    float s = 0.f;
#pragma unroll
    for (int r = 0; r < NREG; ++r)
        s = (__builtin_popcount((unsigned)r & MR) & 1) ? s - pr[r] : s + pr[r];
    return s;
}

template<int W = 0>
__device__ __forceinline__ void measure_all(const float (&pr)[NREG], int lane,
                                            float (&ev)[NQ]) {
    if constexpr (W < NQ) {
        constexpr unsigned m  = ring2_mask(W);
        constexpr unsigned mr = (m >> 6) & 0xFu;   // register-bit part
        constexpr unsigned ml = m & 63u;           // lane-bit part
        float s = regsum16<mr>(pr);
        if constexpr (ml != 0) {
            const unsigned flip = (unsigned)((__popc(lane & (int)ml) & 1)) << 31;
            s = __uint_as_float(__float_as_uint(s) ^ flip);
        }
        ev[W] = wave_sum(s);
        measure_all<W + 1>(pr, lane, ev);
    }
}

// ---------- main kernel (single launch) ----------
// (256, 2): grid is capped at 2048 waves = 2/SIMD anyway -> allow 256 VGPRs
__global__ __launch_bounds__(64 * WPB, 2) void qembed(
    const float* __restrict__ z,     // (B, CDIM)
    const float* __restrict__ Win,   // (CDIM, NQ)
    const float* __restrict__ bin,   // (NQ)
    const float* __restrict__ wts,   // (NL, NQ, 3)
    const float* __restrict__ Wout,  // (NQ, CDIM)
    const float* __restrict__ bout,  // (CDIM)
    float* __restrict__ out)         // (B, CDIM)
{
    __shared__ float4 gl4[2][NQ][2];   // layers 1,2 gate matrices (640 B)

    const int wave = threadIdx.x >> 6;
    const int lane = threadIdx.x & 63;
    const int samp = blockIdx.x * WPB + wave;

    // ---- 20 threads build the layer-1/2 gate matrices once per block ----
    if (threadIdx.x < 2 * NQ) {
        const int li = threadIdx.x / NQ, q = threadIdx.x % NQ;
        const float* wp = wts + ((li + 1) * NQ + q) * 3;
        const float phi = wp[0], th = wp[1], om = wp[2];
        float st, ct, sA, cA, sB, cB;
        __sincosf(0.5f * th, &st, &ct);
        __sincosf(0.5f * (phi + om), &sA, &cA);
        __sincosf(0.5f * (phi - om), &sB, &cB);
        gl4[li][q][0] = make_float4( ct * cA, -ct * sA, -st * cB, -st * sB);
        gl4[li][q][1] = make_float4( st * cB, -st * sB,  ct * cA,  ct * sA);
    }

    // ---- angles = z[samp] @ Win + bin (z as 3x float4, packed acc) ----
    float ang[NQ];
    {
        const float4* z4 = (const float4*)(z + (size_t)samp * CDIM);
        float4 zr[3];
#pragma unroll
        for (int j = 0; j < 3; ++j) zr[j] = z4[lane + j * 64];

        f2 a5[NQ / 2];
#pragma unroll
        for (int h = 0; h < NQ / 2; ++h) a5[h] = (f2){0.f, 0.f};
#pragma unroll
        for (int j = 0; j < 3; ++j) {
            const float zc[4] = {zr[j].x, zr[j].y, zr[j].z, zr[j].w};
#pragma unroll
            for (int c = 0; c < 4; ++c) {
                const int k = 4 * (lane + j * 64) + c;
                const f2* wr = (const f2*)(Win + k * NQ);   // k*10 even -> 8B aligned
#pragma unroll
                for (int h = 0; h < NQ / 2; ++h) a5[h] += wr[h] * zc[c];
            }
        }
#pragma unroll
        for (int h = 0; h < NQ / 2; ++h) {
            ang[2 * h]     = wave_sum(a5[h].x) + bin[2 * h];
            ang[2 * h + 1] = wave_sum(a5[h].y) + bin[2 * h + 1];
        }
    }

    // ---- fused layer-0 gate first columns: F_q = Rot(l0,q)*RX(ang_q) ----
    f2 f0[NQ], f1[NQ];
#pragma unroll
    for (int q = 0; q < NQ; ++q) {
        const float phi = wts[q * 3 + 0];   // uniform -> s_load
        const float th  = wts[q * 3 + 1];
        const float om  = wts[q * 3 + 2];
        float st, ct, sA, cA, sB, cB, s, c;
        __sincosf(0.5f * th, &st, &ct);
        __sincosf(0.5f * (phi + om), &sA, &cA);
        __sincosf(0.5f * (phi - om), &sB, &cB);
        __sincosf(0.5f * ang[q], &s, &c);
        const float g00x =  ct * cA, g00y = -ct * sA;
        const float g01x = -st * cB, g01y = -st * sB;
        const float g10x =  st * cB, g10y = -st * sB;
        const float g11x =  ct * cA, g11y =  ct * sA;
        f2 a, b;
        a.x = g00x * c + s * g01y;  a.y = g00y * c - s * g01x;
        b.x = g10x * c + s * g11y;  b.y = g10y * c - s * g11x;
        f0[q] = a; f1[q] = b;
    }

    // ---- product state built POST-ring-0 (ring 0 absorbed) ----
    // Ring-0 inverse: x_j = y_j^y_{j+1} (j=0..7), x8 = y0^y8^y9, x9 = y0^y9.
    // y bits: 0..5 = lane bits, 6..9 = reg bits r0..r3. Wire w <-> orig bit 9-w.
    const int gray = lane ^ (lane >> 1);
    const int l0 = lane & 1;
    const int l5 = (lane >> 5) & 1;
    f2 G0 = ((gray >> 0) & 1) ? f1[9] : f0[9];
    f2 G1 = ((gray >> 1) & 1) ? f1[8] : f0[8];
    f2 G2 = ((gray >> 2) & 1) ? f1[7] : f0[7];
    f2 G3 = ((gray >> 3) & 1) ? f1[6] : f0[6];
    f2 G4 = ((gray >> 4) & 1) ? f1[5] : f0[5];
    const f2 L5 = cmul(cmul(G0, G1), cmul(G2, cmul(G3, G4)));
    f2 B5[2];
    B5[0] = l5 ? f1[4] : f0[4];
    B5[1] = l5 ? f0[4] : f1[4];
    f2 D8[2], E9[2];
    D8[0] = l0 ? f1[1] : f0[1];
    D8[1] = l0 ? f0[1] : f1[1];
    E9[0] = l0 ? f1[0] : f0[0];
    E9[1] = l0 ? f0[0] : f1[0];

    f2 P1[2];
    P1[0] = cmul(L5, B5[0]);
    P1[1] = cmul(L5, B5[1]);
    f2 P2[4];   // index r0 + 2*r1; orig bit 6 (wire 3): t = r0^r1
#pragma unroll
    for (int r1b = 0; r1b < 2; ++r1b)
#pragma unroll
        for (int r0b = 0; r0b < 2; ++r0b)
            P2[r0b + 2 * r1b] = cmul(P1[r0b], (r0b ^ r1b) ? f1[3] : f0[3]);
    f2 P3[8];   // index r0 + 2*r1 + 4*r2; orig bit 7 (wire 2): t = r1^r2
#pragma unroll
    for (int r2b = 0; r2b < 2; ++r2b)
#pragma unroll
        for (int p = 0; p < 4; ++p)
            P3[p + 4 * r2b] = cmul(P2[p], (((p >> 1) & 1) ^ r2b) ? f1[2] : f0[2]);
    f2 W[4];    // index (r2^r3) + 2*r3
#pragma unroll
    for (int d = 0; d < 2; ++d)
#pragma unroll
        for (int u = 0; u < 2; ++u)
            W[u + 2 * d] = cmul(D8[u], E9[d]);

    f2 v[NREG];
#pragma unroll
    for (int r = 0; r < NREG; ++r) {
        const int r2b = (r >> 2) & 1, r3b = (r >> 3) & 1;
        v[r] = cmul(P3[r & 7], W[(r2b ^ r3b) + 2 * r3b]);
    }

    __syncthreads();   // gl4 ready

    // ---- layers 1..2 from LDS (code once); rings 0,2 absorbed ----
#pragma unroll 1
    for (int l = 0; l < 2; ++l) {
        rot_layer_lds(v, lane, &gl4[l][0][0]);
        if (l == 0) cnot_ring<1>(v, lane);
    }

    // ---- expectation values with ring-2 parity masks ----
    float pr[NREG];
#pragma unroll
    for (int r = 0; r < NREG; ++r) pr[r] = v[r].x * v[r].x + v[r].y * v[r].y;

    float ev[NQ];
    measure_all(pr, lane, ev);

    // ---- out[samp] = ev @ Wout + bout (3 batched chunks, code once) ----
#pragma unroll 1
    for (int ch = 0; ch < 3; ++ch) {
        float wr[4][NQ];
        float bo[4];
#pragma unroll
        for (int j = 0; j < 4; ++j) {
            const int d = lane + (ch * 4 + j) * 64;
            bo[j] = bout[d];
#pragma unroll
            for (int q = 0; q < NQ; ++q) wr[j][q] = Wout[q * CDIM + d];
        }
#pragma unroll
        for (int j = 0; j < 4; ++j) {
            const int d = lane + (ch * 4 + j) * 64;
            float o = bo[j];
#pragma unroll
            for (int q = 0; q < NQ; ++q) o += ev[q] * wr[j][q];
            out[(size_t)samp * CDIM + d] = o;
        }
    }
}

extern "C" void kernel_launch(void* const* d_in, const int* in_sizes, int n_in,
                              void* d_out, int out_size, void* d_ws, size_t ws_size,
                              hipStream_t stream) {
    const float* z    = (const float*)d_in[0];
    const float* Win  = (const float*)d_in[1];
    const float* bin  = (const float*)d_in[2];
    const float* wts  = (const float*)d_in[3];
    const float* Wout = (const float*)d_in[4];
    const float* bout = (const float*)d_in[5];
    float* outp       = (float*)d_out;

    const int batch  = in_sizes[0] / CDIM;   // 2048
    const int blocks = batch / WPB;          // 512
    qembed<<<blocks, 64 * WPB, 0, stream>>>(z, Win, bin, wts, Wout, bout, outp);
}

// Round 13
// 27.175 us; speedup vs baseline: 1.2731x; 1.0100x over previous
//
#include <hip/hip_runtime.h>

typedef float f2 __attribute__((ext_vector_type(2)));   // complex (re, im)
typedef float f4 __attribute__((ext_vector_type(4)));

constexpr int NQ   = 10;
constexpr int CDIM = 768;
constexpr int NL   = 3;
constexpr int NREG = 16;   // index bits 6..9 in the register index
constexpr int WPB  = 4;    // waves (= samples) per block

// ---------- cross-lane primitives (all VALU, no LDS pipe) ----------

template<int CTRL>
__device__ __forceinline__ float dppmov(float x) {
    return __int_as_float(__builtin_amdgcn_update_dpp(
        __float_as_int(x), __float_as_int(x), CTRL, 0xF, 0xF, true));
}

// y[l] = x[l ^ MASK] for MASK in {1,2,4,8}
template<int MASK>
__device__ __forceinline__ float lxor(float x, int lane) {
    static_assert(MASK == 1 || MASK == 2 || MASK == 4 || MASK == 8, "");
    if constexpr (MASK == 1)      return dppmov<0xB1>(x);   // quad_perm [1,0,3,2]
    else if constexpr (MASK == 2) return dppmov<0x4E>(x);   // quad_perm [2,3,0,1]
    else if constexpr (MASK == 4) {
        const float a = dppmov<0x104>(x);   // row_shl:4 -> src[i+4] (bit2=0 lanes)
        const float b = dppmov<0x114>(x);   // row_shr:4 -> src[i-4] (bit2=1 lanes)
        return ((lane >> 2) & 1) ? b : a;
    }
    else                          return dppmov<0x128>(x);  // row_ror:8 == xor8
}

// B in {4,5}: lo = x[l & ~(1<<B)], hi = x[l | (1<<B)]  (one swap instr)
template<int B>
__device__ __forceinline__ void swap2(float x, float& lo, float& hi) {
    const unsigned xu = __float_as_uint(x);
#if __has_builtin(__builtin_amdgcn_permlane16_swap) && __has_builtin(__builtin_amdgcn_permlane32_swap)
    if constexpr (B == 4) {
        auto r = __builtin_amdgcn_permlane16_swap(xu, xu, false, false);
        lo = __uint_as_float(r[0]); hi = __uint_as_float(r[1]);
    } else {
        auto r = __builtin_amdgcn_permlane32_swap(xu, xu, false, false);
        lo = __uint_as_float(r[0]); hi = __uint_as_float(r[1]);
    }
#else
    float d, s;
    if constexpr (B == 4)
        asm("v_mov_b32 %0, %2\n\tv_mov_b32 %1, %2\n\ts_nop 1\n\t"
            "v_permlane16_swap_b32 %0, %1"
            : "=&v"(d), "=&v"(s) : "v"(x));
    else
        asm("v_mov_b32 %0, %2\n\tv_mov_b32 %1, %2\n\ts_nop 1\n\t"
            "v_permlane32_swap_b32 %0, %1"
            : "=&v"(d), "=&v"(s) : "v"(x));
    lo = d; hi = s;
#endif
}

__device__ __forceinline__ float wave_sum(float v) {
    v += dppmov<0xB1>(v);    // xor1
    v += dppmov<0x4E>(v);    // xor2
    v += dppmov<0x141>(v);   // row_half_mirror = xor7 (bits 0-1 uniform)
    v += dppmov<0x140>(v);   // row_mirror = xor15 (bits 0-2 uniform)
    float lo, hi;
    swap2<4>(v, lo, hi); v = lo + hi;
    swap2<5>(v, lo, hi); v = lo + hi;
    return v;
}

// ---------- complex helpers (packed-math friendly) ----------

__device__ __forceinline__ f2 swapneg(f2 b) { f2 r; r.x = -b.y; r.y = b.x; return r; }
__device__ __forceinline__ f2 cmul(f2 a, f2 b) { return b * a.x + swapneg(b) * a.y; }
__device__ __forceinline__ f2 cfma(f2 a, f2 b, f2 acc) { return acc + b * a.x + swapneg(b) * a.y; }

// ---------- 1-qubit gate on index-bit B (wire w -> B = 9 - w) ----------

template<int B>
__device__ __forceinline__ void gate_bit(f2 (&v)[NREG], int lane,
                                         f2 g00, f2 g01, f2 g10, f2 g11) {
    if constexpr (B >= 6) {                       // register bit: pure in-reg
        constexpr int rb = B - 6;
#pragma unroll
        for (int p = 0; p < NREG / 2; ++p) {
            const int r0 = ((p >> rb) << (rb + 1)) | (p & ((1 << rb) - 1));
            const int r1 = r0 | (1 << rb);
            const f2 a0 = v[r0], a1 = v[r1];
            v[r0] = cfma(g01, a1, cmul(g00, a0));
            v[r1] = cfma(g11, a1, cmul(g10, a0));
        }
    } else if constexpr (B >= 4) {                // lane bit via permlane swap
        const bool hb = (lane >> B) & 1;
        const f2 A  = hb ? g10 : g00;             // coeff on lo value
        const f2 Bc = hb ? g11 : g01;             // coeff on hi value
#pragma unroll
        for (int r = 0; r < NREG; ++r) {
            float lx, hx, ly, hy;
            swap2<B>(v[r].x, lx, hx);
            swap2<B>(v[r].y, ly, hy);
            f2 lo; lo.x = lx; lo.y = ly;
            f2 hi; hi.x = hx; hi.y = hy;
            v[r] = cfma(Bc, hi, cmul(A, lo));
        }
    } else {                                      // lane bit via DPP
        const bool hb = (lane >> B) & 1;
        const f2 cO = hb ? g11 : g00;
        const f2 cP = hb ? g10 : g01;
#pragma unroll
        for (int r = 0; r < NREG; ++r) {
            f2 p;
            p.x = lxor<(1 << B)>(v[r].x, lane);
            p.y = lxor<(1 << B)>(v[r].y, lane);
            v[r] = cfma(cP, p, cmul(cO, v[r]));
        }
    }
}

// partner value x[l ^ (1<<BT)] for lane-resident target bit
template<int BT>
__device__ __forceinline__ float partner(float x, int lane) {
    if constexpr (BT >= 4) {
        float lo, hi; swap2<BT>(x, lo, hi);
        return ((lane >> BT) & 1) ? lo : hi;
    } else return lxor<(1 << BT)>(x, lane);
}

// ---------- CNOT ----------

template<int BC, int BT>
__device__ __forceinline__ void cnot(f2 (&v)[NREG], int lane) {
    if constexpr (BC >= 6 && BT >= 6) {           // both reg: free rename
        constexpr int rc = BC - 6, rt = BT - 6;
#pragma unroll
        for (int r = 0; r < NREG; ++r)
            if (((r >> rc) & 1) && !((r >> rt) & 1)) {
                const int r1 = r | (1 << rt);
                const f2 t = v[r]; v[r] = v[r1]; v[r1] = t;
            }
    } else if constexpr (BC >= 6) {               // reg control, lane target
        constexpr int rc = BC - 6;
#pragma unroll
        for (int r = 0; r < NREG; ++r)
            if ((r >> rc) & 1) {
                f2 n;
                n.x = partner<BT>(v[r].x, lane);
                n.y = partner<BT>(v[r].y, lane);
                v[r] = n;
            }
    } else if constexpr (BT >= 6) {               // lane control, reg target
        constexpr int rt = BT - 6;
        const bool c = (lane >> BC) & 1;
#pragma unroll
        for (int p = 0; p < NREG / 2; ++p) {
            const int r0 = ((p >> rt) << (rt + 1)) | (p & ((1 << rt) - 1));
            const int r1 = r0 | (1 << rt);
            const f2 a = v[r0], b = v[r1];
            v[r0] = c ? b : a;
            v[r1] = c ? a : b;
        }
    } else {                                      // both lane
        const bool c = (lane >> BC) & 1;
#pragma unroll
        for (int r = 0; r < NREG; ++r) {
            f2 n;
            n.x = c ? partner<BT>(v[r].x, lane) : v[r].x;
            n.y = c ? partner<BT>(v[r].y, lane) : v[r].y;
            v[r] = n;
        }
    }
}

// ---------- rot layer from LDS matrices (code emitted ONCE, looped) ----------

template<int Q = 0>
__device__ __forceinline__ void rot_layer_lds(f2 (&v)[NREG], int lane,
                                              const float4* g /*LDS, [NQ][2]*/) {
    if constexpr (Q < NQ) {
        const float4 p0 = g[Q * 2];        // broadcast ds_read_b128
        const float4 p1 = g[Q * 2 + 1];
        f2 g00 = {p0.x, p0.y}, g01 = {p0.z, p0.w};
        f2 g10 = {p1.x, p1.y}, g11 = {p1.z, p1.w};
        gate_bit<9 - Q>(v, lane, g00, g01, g10, g11);
        rot_layer_lds<Q + 1>(v, lane, g);
    }
}

template<int L, int I = 0>
__device__ __forceinline__ void cnot_ring(f2 (&v)[NREG], int lane) {
    if constexpr (I < NQ) {
        constexpr int R = (L % (NQ - 1)) + 1;
        cnot<9 - I, 9 - ((I + R) % NQ)>(v, lane);
        cnot_ring<L, I + 1>(v, lane);
    }
}

// ---------- ring-2 absorbed measurement ----------
constexpr unsigned ring2_mask(int w) {
    unsigned M[NQ] = {};
    for (int i = 0; i < NQ; ++i) M[i] = 1u << (9 - i);
    for (int i = 0; i < NQ; ++i) M[(i + 3) % NQ] ^= M[i];
    return M[w];
}

template<unsigned MR>
__device__ __forceinline__ float regsum16(const float (&pr)[NREG]) {
    float s = 0.f;
#pragma unroll
    for (int r = 0; r < NREG; ++r)
        s = (__builtin_popcount((unsigned)r & MR) & 1) ? s - pr[r] : s + pr[r];
    return s;
}

template<int W = 0>
__device__ __forceinline__ void measure_all(const float (&pr)[NREG], int lane,
                                            float (&ev)[NQ]) {
    if constexpr (W < NQ) {
        constexpr unsigned m  = ring2_mask(W);
        constexpr unsigned mr = (m >> 6) & 0xFu;   // register-bit part
        constexpr unsigned ml = m & 63u;           // lane-bit part
        float s = regsum16<mr>(pr);
        if constexpr (ml != 0) {
            const unsigned flip = (unsigned)((__popc(lane & (int)ml) & 1)) << 31;
            s = __uint_as_float(__float_as_uint(s) ^ flip);
        }
        ev[W] = wave_sum(s);
        measure_all<W + 1>(pr, lane, ev);
    }
}

// ---------- main kernel (single launch) ----------
// (256, 2): grid is capped at 2048 waves = 2/SIMD anyway -> allow 256 VGPRs
__global__ __launch_bounds__(64 * WPB, 2) void qembed(
    const float* __restrict__ z,     // (B, CDIM)
    const float* __restrict__ Win,   // (CDIM, NQ)
    const float* __restrict__ bin,   // (NQ)
    const float* __restrict__ wts,   // (NL, NQ, 3)
    const float* __restrict__ Wout,  // (NQ, CDIM)
    const float* __restrict__ bout,  // (CDIM)
    float* __restrict__ out)         // (B, CDIM)
{
    __shared__ float4 gl4[NL][NQ][2];   // all 3 layers' gate matrices (960 B)

    const int wave = threadIdx.x >> 6;
    const int lane = threadIdx.x & 63;
    const int samp = blockIdx.x * WPB + wave;

    // ---- 30 threads build all gate matrices once per block ----
    if (threadIdx.x < NL * NQ) {
        const int li = threadIdx.x / NQ, q = threadIdx.x % NQ;
        const float* wp = wts + (li * NQ + q) * 3;
        const float phi = wp[0], th = wp[1], om = wp[2];
        float st, ct, sA, cA, sB, cB;
        __sincosf(0.5f * th, &st, &ct);
        __sincosf(0.5f * (phi + om), &sA, &cA);
        __sincosf(0.5f * (phi - om), &sB, &cB);
        gl4[li][q][0] = make_float4( ct * cA, -ct * sA, -st * cB, -st * sB);
        gl4[li][q][1] = make_float4( st * cB, -st * sB,  ct * cA,  ct * sA);
    }

    // ---- angles = z[samp] @ Win + bin (consecutive-k, dwordx4 loads) ----
    float ang[NQ];
    {
        const float* zrow = z + (size_t)samp * CDIM;
        f2 a5[NQ / 2];
#pragma unroll
        for (int h = 0; h < NQ / 2; ++h) a5[h] = (f2){0.f, 0.f};
#pragma unroll
        for (int j = 0; j < 3; ++j) {
            const int kb = 4 * (lane + 64 * j);        // 4 consecutive k rows
            const float4 zv = *(const float4*)(zrow + kb);
            float w40[40];
#pragma unroll
            for (int t = 0; t < 10; ++t) {
                const float4 u = *(const float4*)(Win + (size_t)kb * NQ + 4 * t);
                w40[4 * t] = u.x; w40[4 * t + 1] = u.y;
                w40[4 * t + 2] = u.z; w40[4 * t + 3] = u.w;
            }
            const float zc[4] = {zv.x, zv.y, zv.z, zv.w};
#pragma unroll
            for (int c = 0; c < 4; ++c)
#pragma unroll
                for (int h = 0; h < NQ / 2; ++h) {
                    f2 w; w.x = w40[c * 10 + 2 * h]; w.y = w40[c * 10 + 2 * h + 1];
                    a5[h] += w * zc[c];
                }
        }
#pragma unroll
        for (int h = 0; h < NQ / 2; ++h) {
            ang[2 * h]     = wave_sum(a5[h].x) + bin[2 * h];
            ang[2 * h + 1] = wave_sum(a5[h].y) + bin[2 * h + 1];
        }
    }

    __syncthreads();   // gl4 ready

    // ---- fused layer-0 first columns from LDS: F_q = Rot(l0,q)*RX(ang_q) ----
    f2 f0[NQ], f1[NQ];
#pragma unroll
    for (int q = 0; q < NQ; ++q) {
        const float4 p0 = gl4[0][q][0];    // A=(x,y) B=(z,w)
        const float4 p1 = gl4[0][q][1];    // C=(x,y) D=(z,w)
        float s, c;
        __sincosf(0.5f * ang[q], &s, &c);
        f2 a, b;
        a.x = p0.x * c + s * p0.w;  a.y = p0.y * c - s * p0.z;
        b.x = p1.x * c + s * p1.w;  b.y = p1.y * c - s * p1.z;
        f0[q] = a; f1[q] = b;
    }

    // ---- product state built POST-ring-0 (ring 0 absorbed) ----
    // Ring-0 inverse: x_j = y_j^y_{j+1} (j=0..7), x8 = y0^y8^y9, x9 = y0^y9.
    // y bits: 0..5 = lane bits, 6..9 = reg bits r0..r3. Wire w <-> orig bit 9-w.
    const int gray = lane ^ (lane >> 1);
    const int l0 = lane & 1;
    const int l5 = (lane >> 5) & 1;
    f2 G0 = ((gray >> 0) & 1) ? f1[9] : f0[9];
    f2 G1 = ((gray >> 1) & 1) ? f1[8] : f0[8];
    f2 G2 = ((gray >> 2) & 1) ? f1[7] : f0[7];
    f2 G3 = ((gray >> 3) & 1) ? f1[6] : f0[6];
    f2 G4 = ((gray >> 4) & 1) ? f1[5] : f0[5];
    const f2 L5 = cmul(cmul(G0, G1), cmul(G2, cmul(G3, G4)));
    f2 B5[2];
    B5[0] = l5 ? f1[4] : f0[4];
    B5[1] = l5 ? f0[4] : f1[4];
    f2 D8[2], E9[2];
    D8[0] = l0 ? f1[1] : f0[1];
    D8[1] = l0 ? f0[1] : f1[1];
    E9[0] = l0 ? f1[0] : f0[0];
    E9[1] = l0 ? f0[0] : f1[0];

    f2 P1[2];
    P1[0] = cmul(L5, B5[0]);
    P1[1] = cmul(L5, B5[1]);
    f2 P2[4];   // index r0 + 2*r1; orig bit 6 (wire 3): t = r0^r1
#pragma unroll
    for (int r1b = 0; r1b < 2; ++r1b)
#pragma unroll
        for (int r0b = 0; r0b < 2; ++r0b)
            P2[r0b + 2 * r1b] = cmul(P1[r0b], (r0b ^ r1b) ? f1[3] : f0[3]);
    f2 P3[8];   // index r0 + 2*r1 + 4*r2; orig bit 7 (wire 2): t = r1^r2
#pragma unroll
    for (int r2b = 0; r2b < 2; ++r2b)
#pragma unroll
        for (int p = 0; p < 4; ++p)
            P3[p + 4 * r2b] = cmul(P2[p], (((p >> 1) & 1) ^ r2b) ? f1[2] : f0[2]);
    f2 W[4];    // index (r2^r3) + 2*r3
#pragma unroll
    for (int d = 0; d < 2; ++d)
#pragma unroll
        for (int u = 0; u < 2; ++u)
            W[u + 2 * d] = cmul(D8[u], E9[d]);

    f2 v[NREG];
#pragma unroll
    for (int r = 0; r < NREG; ++r) {
        const int r2b = (r >> 2) & 1, r3b = (r >> 3) & 1;
        v[r] = cmul(P3[r & 7], W[(r2b ^ r3b) + 2 * r3b]);
    }

    // ---- layers 1..2 from LDS (code once); rings 0,2 absorbed ----
#pragma unroll 1
    for (int l = 0; l < 2; ++l) {
        rot_layer_lds(v, lane, &gl4[l + 1][0][0]);
        if (l == 0) cnot_ring<1>(v, lane);
    }

    // ---- expectation values with ring-2 parity masks ----
    float pr[NREG];
#pragma unroll
    for (int r = 0; r < NREG; ++r) pr[r] = v[r].x * v[r].x + v[r].y * v[r].y;

    float ev[NQ];
    measure_all(pr, lane, ev);

    // ---- out[samp] = ev @ Wout + bout (float4 columns, code once) ----
#pragma unroll 1
    for (int ch = 0; ch < 3; ++ch) {
        const int d0 = ch * 256 + lane * 4;
        f4 w4[NQ];
#pragma unroll
        for (int q = 0; q < NQ; ++q) w4[q] = *(const f4*)(Wout + q * CDIM + d0);
        f4 o = *(const f4*)(bout + d0);
#pragma unroll
        for (int q = 0; q < NQ; ++q) o += w4[q] * ev[q];
        *(f4*)(out + (size_t)samp * CDIM + d0) = o;
    }
}

extern "C" void kernel_launch(void* const* d_in, const int* in_sizes, int n_in,
                              void* d_out, int out_size, void* d_ws, size_t ws_size,
                              hipStream_t stream) {
    const float* z    = (const float*)d_in[0];
    const float* Win  = (const float*)d_in[1];
    const float* bin  = (const float*)d_in[2];
    const float* wts  = (const float*)d_in[3];
    const float* Wout = (const float*)d_in[4];
    const float* bout = (const float*)d_in[5];
    float* outp       = (float*)d_out;

    const int batch  = in_sizes[0] / CDIM;   // 2048
    const int blocks = batch / WPB;          // 512
    qembed<<<blocks, 64 * WPB, 0, stream>>>(z, Win, bin, wts, Wout, bout, outp);
}